// Round 4
// baseline (1194.133 us; speedup 1.0000x reference)
//
#include <hip/hip_runtime.h>
#include <math.h>

// ---------------------------------------------------------------------------
// IPMPEncoder, zero-workspace + runtime dtype-probing version.
// Two fused kernels (node pass EDGE=0, edge pass EDGE=1), each templated on
// BF (true: float tensors are bf16; false: f32). Every block probes h_V's raw
// bits to decide which variant runs; the other returns immediately.
// Inter-pass h_V is carried through d_out (its h_V region), so d_ws is unused.
// ---------------------------------------------------------------------------

#define Bb  2
#define Lb  2048
#define Kb  32
#define Hb  128
#define Pb  8
#define Nn  (Bb * Lb)
#define MSG 456

typedef unsigned short u16;
typedef __attribute__((ext_vector_type(4))) unsigned short us4;
typedef __attribute__((ext_vector_type(8))) unsigned short us8;

__device__ __forceinline__ float u2f(u16 u) {
    union { unsigned int i; float f; } v; v.i = ((unsigned int)u) << 16; return v.f;
}
__device__ __forceinline__ u16 f2b(float x) {
    union { float f; unsigned int i; } v; v.f = x;
    unsigned int r = v.i + 0x7FFFu + ((v.i >> 16) & 1u);  // RNE
    return (u16)(r >> 16);
}
__device__ __forceinline__ float gelu_f(float x) {
    return 0.5f * x * (1.0f + erff(x * 0.7071067811865476f));
}

template <bool BF>
__device__ __forceinline__ float ld(const void* p, size_t i) {
    if constexpr (BF) return u2f(((const u16*)p)[i]);
    else              return ((const float*)p)[i];
}
template <bool BF>
__device__ __forceinline__ void ld4(const void* p, size_t i, float o[4]) {
    if constexpr (BF) {
        us4 u = *(const us4*)((const u16*)p + i);
        o[0] = u2f(u[0]); o[1] = u2f(u[1]); o[2] = u2f(u[2]); o[3] = u2f(u[3]);
    } else {
        const float* f = (const float*)p + i;
        o[0] = f[0]; o[1] = f[1]; o[2] = f[2]; o[3] = f[3];
    }
}

struct Args { const void* p[32]; };
enum { I_HV = 0, I_HE, I_EIDX, I_X, I_MV, I_MA, I_WPN, I_BPN, I_WPE, I_BPE,
       I_W1, I_B1, I_W2, I_B2, I_W3, I_B3, I_W11, I_B11, I_W12, I_B12,
       I_W13, I_B13, I_WDI, I_BDI, I_WDO, I_BDO,
       I_G1, I_BE1, I_G2, I_BE2, I_G3, I_BE3 };

// Reference frames: e0=unit(CA-N), e1=unit(ortho(C-CA)), e2=e0xe1,
// R[coord][basis], t=CA.
template <bool BF>
__device__ __forceinline__ void frames(const void* X, int g, float R[9], float tt[3]) {
    float Na[3], CA[3], Cc[3];
#pragma unroll
    for (int d = 0; d < 3; ++d) {
        Na[d] = ld<BF>(X, (size_t)g * 12 + d);
        CA[d] = ld<BF>(X, (size_t)g * 12 + 3 + d);
        Cc[d] = ld<BF>(X, (size_t)g * 12 + 6 + d);
    }
    float e0[3], e1[3], e2[3];
#pragma unroll
    for (int d = 0; d < 3; ++d) e0[d] = CA[d] - Na[d];
    float s = e0[0]*e0[0] + e0[1]*e0[1] + e0[2]*e0[2];
    float inv = 1.0f / sqrtf(s + 1e-8f);
#pragma unroll
    for (int d = 0; d < 3; ++d) e0[d] *= inv;
#pragma unroll
    for (int d = 0; d < 3; ++d) e1[d] = Cc[d] - CA[d];
    float d01 = e0[0]*e1[0] + e0[1]*e1[1] + e0[2]*e1[2];
#pragma unroll
    for (int d = 0; d < 3; ++d) e1[d] -= e0[d] * d01;
    s = e1[0]*e1[0] + e1[1]*e1[1] + e1[2]*e1[2];
    inv = 1.0f / sqrtf(s + 1e-8f);
#pragma unroll
    for (int d = 0; d < 3; ++d) e1[d] *= inv;
    e2[0] = e0[1]*e1[2] - e0[2]*e1[1];
    e2[1] = e0[2]*e1[0] - e0[0]*e1[2];
    e2[2] = e0[0]*e1[1] - e0[1]*e1[0];
#pragma unroll
    for (int d = 0; d < 3; ++d) {
        R[d*3 + 0] = e0[d]; R[d*3 + 1] = e1[d]; R[d*3 + 2] = e2[d];
        tt[d] = CA[d];
    }
}

// p_local[3] for (node g, virtual point p): hV[g] @ Wp[:, 3p..3p+2] + bp.
template <bool BF>
__device__ __forceinline__ void plocal(const void* hV, const void* Wp, const void* bp,
                                       int g, int p, float o[3]) {
    float a0 = ld<BF>(bp, p*3 + 0), a1 = ld<BF>(bp, p*3 + 1), a2 = ld<BF>(bp, p*3 + 2);
    for (int i = 0; i < Hb; ++i) {
        float h = ld<BF>(hV, (size_t)g * Hb + i);
        a0 += h * ld<BF>(Wp, (size_t)i * 24 + p*3 + 0);
        a1 += h * ld<BF>(Wp, (size_t)i * 24 + p*3 + 1);
        a2 += h * ld<BF>(Wp, (size_t)i * 24 + p*3 + 2);
    }
    o[0] = a0; o[1] = a1; o[2] = a2;
}

__device__ __forceinline__ float block_sum128(float x, float* r1, float* redv, int t) {
    if (t < Hb) r1[t] = x;
    __syncthreads();
    if (t < 64) r1[t] += r1[t + 64];
    __syncthreads();
    if (t < 64) {
        float s = r1[t];
        s += __shfl_down(s, 32); s += __shfl_down(s, 16);
        s += __shfl_down(s, 8);  s += __shfl_down(s, 4);
        s += __shfl_down(s, 2);  s += __shfl_down(s, 1);
        if (t == 0) redv[0] = s;
    }
    __syncthreads();
    float r = redv[0];
    __syncthreads();
    return r;
}

// ---------------------------------------------------------------------------
template <int EDGE, bool BF>
__global__ __launch_bounds__(256)
void k_msg(Args A, const void* hVsrc, void* dout) {
    const int n = blockIdx.x;
    const int bidx = n >> 11;          // n / Lb
    const int t = threadIdx.x;

    __shared__ u16   mi[Kb][MSG];      // 29184 B
    __shared__ float mbuf[Kb][Hb];     // 16384 B
    __shared__ float cR[9], ct[3], cpl[24], cpg[24], cpn[8];
    __shared__ float hn[Hb], ffb[4 * Hb], r1[Hb], redv[1];
    __shared__ int   sh_wild, sh_zero;

    const int* Ei = (const int*)A.p[I_EIDX];

    // ---- dtype probe: raw u16 stats on h_V, odd-word zeros on E_idx ----
    if (t == 0) { sh_wild = 0; sh_zero = 0; }
    __syncthreads();
    {
        const u16* hv_raw = (const u16*)A.p[I_HV];
        int wild = 0;
#pragma unroll
        for (int k = 0; k < 2; ++k) {
            u16 u = hv_raw[t * 2 + k];
            int e = (u >> 7) & 0xFF;
            if (e == 0xFF || (e != 0 && (e < 64 || e > 190))) wild++;
        }
        if (wild) atomicAdd(&sh_wild, wild);
        if (Ei[t * 2 + 1] == 0) atomicAdd(&sh_zero, 1);
    }
    __syncthreads();
    const bool isBF  = (sh_wild < 26);   // bf16 world: ~0 wild of 512
    const bool idx64 = (sh_zero > 128);  // int64 world: all 256 odd words zero
    if (isBF != BF) return;              // uniform exit, no later barriers run

    const void* hEp = A.p[I_HE];
    const void* Xp  = A.p[I_X];
    const void* Wpp = EDGE ? A.p[I_WPE] : A.p[I_WPN];
    const void* bpp = EDGE ? A.p[I_BPE] : A.p[I_BPN];
    const void* W1p = EDGE ? A.p[I_W11] : A.p[I_W1];
    const void* b1p = EDGE ? A.p[I_B11] : A.p[I_B1];
    const void* W2p = EDGE ? A.p[I_W12] : A.p[I_W2];
    const void* b2p = EDGE ? A.p[I_B12] : A.p[I_B2];
    const void* W3p = EDGE ? A.p[I_W13] : A.p[I_W3];
    const void* b3p = EDGE ? A.p[I_B13] : A.p[I_B3];
    const void* gAp  = EDGE ? A.p[I_G3]  : A.p[I_G1];
    const void* beAp = EDGE ? A.p[I_BE3] : A.p[I_BE1];

    // ---- center frame + virtual points ----
    if (t < 8) {
        float R[9], tt[3];
        frames<BF>(Xp, n, R, tt);
        if (t == 0) {
#pragma unroll
            for (int k2 = 0; k2 < 9; ++k2) cR[k2] = R[k2];
#pragma unroll
            for (int d = 0; d < 3; ++d) ct[d] = tt[d];
        }
        float pl3[3];
        plocal<BF>(hVsrc, Wpp, bpp, n, t, pl3);
#pragma unroll
        for (int d = 0; d < 3; ++d) cpl[t*3 + d] = pl3[d];
        cpn[t] = sqrtf(pl3[0]*pl3[0] + pl3[1]*pl3[1] + pl3[2]*pl3[2] + 1e-8f);
#pragma unroll
        for (int i = 0; i < 3; ++i)
            cpg[t*3 + i] = R[i*3+0]*pl3[0] + R[i*3+1]*pl3[1] + R[i*3+2]*pl3[2] + tt[i];
    }
    __syncthreads();

    // ---- Stage A: message rows, 8 threads/edge ----
    {
        const int e = t >> 3, j = t & 7;
        const int gE = n * Kb + e;
        const int nbr = idx64 ? Ei[(size_t)gE * 2] : Ei[gE];
        const int jg = bidx * Lb + nbr;
        const size_t hv_c = (size_t)n * Hb, hv_n = (size_t)jg * Hb, he_o = (size_t)gE * Hb;
        const int base = j * 16;
#pragma unroll
        for (int c = 0; c < 16; ++c) {
            mi[e][base + c]       = f2b(ld<BF>(hVsrc, hv_c + base + c));
            mi[e][128 + base + c] = f2b(ld<BF>(hEp,   he_o + base + c));
            mi[e][256 + base + c] = f2b(ld<BF>(hVsrc, hv_n + base + c));
        }
        const int p = j;
#pragma unroll
        for (int d = 0; d < 3; ++d) mi[e][384 + p*3 + d] = f2b(cpl[p*3 + d]);
        mi[e][408 + p] = f2b(cpn[p]);

        float Rn[9], tn[3];
        frames<BF>(Xp, jg, Rn, tn);
        float plb[3];
        plocal<BF>(hVsrc, Wpp, bpp, jg, p, plb);
        float pgn[3];
#pragma unroll
        for (int i = 0; i < 3; ++i)
            pgn[i] = Rn[i*3+0]*plb[0] + Rn[i*3+1]*plb[1] + Rn[i*3+2]*plb[2] + tn[i];
        float v0 = pgn[0] - ct[0], v1 = pgn[1] - ct[1], v2 = pgn[2] - ct[2];
        float l0 = cR[0]*v0 + cR[3]*v1 + cR[6]*v2;   // R^T v
        float l1 = cR[1]*v0 + cR[4]*v1 + cR[7]*v2;
        float l2 = cR[2]*v0 + cR[5]*v1 + cR[8]*v2;
        mi[e][416 + p*3 + 0] = f2b(l0);
        mi[e][416 + p*3 + 1] = f2b(l1);
        mi[e][416 + p*3 + 2] = f2b(l2);
        mi[e][440 + p] = f2b(sqrtf(l0*l0 + l1*l1 + l2*l2 + 1e-8f));
        float d0 = cpg[p*3+0] - pgn[0], d1 = cpg[p*3+1] - pgn[1], d2 = cpg[p*3+2] - pgn[2];
        mi[e][448 + p] = f2b(sqrtf(d0*d0 + d1*d1 + d2*d2 + 1e-8f));
    }
    __syncthreads();

    const int go = t & 31, ge = t >> 5;
    const int o0 = go * 4, eb = ge * 4;

    // ---- GEMM1: (32x456)@(456x128)+b1, gelu ----
    float acc[4][4];
    {
        float c0 = ld<BF>(b1p, o0),   c1 = ld<BF>(b1p, o0+1);
        float c2 = ld<BF>(b1p, o0+2), c3 = ld<BF>(b1p, o0+3);
#pragma unroll
        for (int ei = 0; ei < 4; ++ei) { acc[ei][0]=c0; acc[ei][1]=c1; acc[ei][2]=c2; acc[ei][3]=c3; }
    }
    for (int i0 = 0; i0 < MSG; i0 += 8) {
        float a[4][8];
#pragma unroll
        for (int ei = 0; ei < 4; ++ei) {
            us8 u = *(const us8*)&mi[eb + ei][i0];
#pragma unroll
            for (int ii = 0; ii < 8; ++ii) a[ei][ii] = u2f(u[ii]);
        }
#pragma unroll
        for (int ii = 0; ii < 8; ++ii) {
            float w[4];
            ld4<BF>(W1p, (size_t)(i0 + ii) * Hb + o0, w);
#pragma unroll
            for (int ei = 0; ei < 4; ++ei) {
                acc[ei][0] += a[ei][ii] * w[0];
                acc[ei][1] += a[ei][ii] * w[1];
                acc[ei][2] += a[ei][ii] * w[2];
                acc[ei][3] += a[ei][ii] * w[3];
            }
        }
    }
#pragma unroll
    for (int ei = 0; ei < 4; ++ei)
#pragma unroll
        for (int oi = 0; oi < 4; ++oi) mbuf[eb+ei][o0+oi] = gelu_f(acc[ei][oi]);
    __syncthreads();

    // ---- GEMM2 ----
    float acc2[4][4];
    {
        float c0 = ld<BF>(b2p, o0),   c1 = ld<BF>(b2p, o0+1);
        float c2 = ld<BF>(b2p, o0+2), c3 = ld<BF>(b2p, o0+3);
#pragma unroll
        for (int ei = 0; ei < 4; ++ei) { acc2[ei][0]=c0; acc2[ei][1]=c1; acc2[ei][2]=c2; acc2[ei][3]=c3; }
    }
    for (int i0 = 0; i0 < Hb; i0 += 4) {
        float av[4][4];
#pragma unroll
        for (int ei = 0; ei < 4; ++ei) {
            float4 f = *(const float4*)&mbuf[eb + ei][i0];
            av[ei][0] = f.x; av[ei][1] = f.y; av[ei][2] = f.z; av[ei][3] = f.w;
        }
#pragma unroll
        for (int ii = 0; ii < 4; ++ii) {
            float w[4];
            ld4<BF>(W2p, (size_t)(i0 + ii) * Hb + o0, w);
#pragma unroll
            for (int ei = 0; ei < 4; ++ei) {
                acc2[ei][0] += av[ei][ii] * w[0];
                acc2[ei][1] += av[ei][ii] * w[1];
                acc2[ei][2] += av[ei][ii] * w[2];
                acc2[ei][3] += av[ei][ii] * w[3];
            }
        }
    }
    __syncthreads();
#pragma unroll
    for (int ei = 0; ei < 4; ++ei)
#pragma unroll
        for (int oi = 0; oi < 4; ++oi) mbuf[eb+ei][o0+oi] = gelu_f(acc2[ei][oi]);
    __syncthreads();

    // ---- GEMM3 ----
    float acc3[4][4];
    {
        float c0 = ld<BF>(b3p, o0),   c1 = ld<BF>(b3p, o0+1);
        float c2 = ld<BF>(b3p, o0+2), c3 = ld<BF>(b3p, o0+3);
#pragma unroll
        for (int ei = 0; ei < 4; ++ei) { acc3[ei][0]=c0; acc3[ei][1]=c1; acc3[ei][2]=c2; acc3[ei][3]=c3; }
    }
    for (int i0 = 0; i0 < Hb; i0 += 4) {
        float av[4][4];
#pragma unroll
        for (int ei = 0; ei < 4; ++ei) {
            float4 f = *(const float4*)&mbuf[eb + ei][i0];
            av[ei][0] = f.x; av[ei][1] = f.y; av[ei][2] = f.z; av[ei][3] = f.w;
        }
#pragma unroll
        for (int ii = 0; ii < 4; ++ii) {
            float w[4];
            ld4<BF>(W3p, (size_t)(i0 + ii) * Hb + o0, w);
#pragma unroll
            for (int ei = 0; ei < 4; ++ei) {
                acc3[ei][0] += av[ei][ii] * w[0];
                acc3[ei][1] += av[ei][ii] * w[1];
                acc3[ei][2] += av[ei][ii] * w[2];
                acc3[ei][3] += av[ei][ii] * w[3];
            }
        }
    }
    __syncthreads();

    if (!EDGE) {
        // mask_attend * m
#pragma unroll
        for (int ei = 0; ei < 4; ++ei) {
            float m = ld<BF>(A.p[I_MA], (size_t)n * Kb + eb + ei);
#pragma unroll
            for (int oi = 0; oi < 4; ++oi) mbuf[eb+ei][o0+oi] = acc3[ei][oi] * m;
        }
        __syncthreads();

        float v = 0.f;
        if (t < Hb) {
            float s = 0.f;
#pragma unroll
            for (int e = 0; e < Kb; ++e) s += mbuf[e][t];
            v = ld<BF>(hVsrc, (size_t)n * Hb + t) + s * (1.0f / Kb);
        }
        float mu = block_sum128(v, r1, redv, t) * (1.0f / Hb);
        float d = (t < Hb) ? (v - mu) : 0.f;
        float var = block_sum128(d * d, r1, redv, t) * (1.0f / Hb);
        float rstd = 1.0f / sqrtf(var + 1e-5f);
        if (t < Hb)
            hn[t] = (v - mu) * rstd * ld<BF>(A.p[I_G1], t) + ld<BF>(A.p[I_BE1], t);
        __syncthreads();

        // FFN
        float a0 = ld<BF>(A.p[I_BDI], t), a1 = ld<BF>(A.p[I_BDI], t + 256);
        for (int i = 0; i < Hb; ++i) {
            float h = hn[i];
            a0 += h * ld<BF>(A.p[I_WDI], (size_t)i * 512 + t);
            a1 += h * ld<BF>(A.p[I_WDI], (size_t)i * 512 + t + 256);
        }
        ffb[t] = gelu_f(a0); ffb[t + 256] = gelu_f(a1);
        __syncthreads();
        float v2 = 0.f;
        if (t < Hb) {
            float accf = ld<BF>(A.p[I_BDO], t);
            for (int jj = 0; jj < 512; ++jj)
                accf += ffb[jj] * ld<BF>(A.p[I_WDO], (size_t)jj * Hb + t);
            v2 = hn[t] + accf;
        }
        float mu2 = block_sum128(v2, r1, redv, t) * (1.0f / Hb);
        float d2 = (t < Hb) ? (v2 - mu2) : 0.f;
        float var2 = block_sum128(d2 * d2, r1, redv, t) * (1.0f / Hb);
        float rstd2 = 1.0f / sqrtf(var2 + 1e-5f);
        if (t < Hb) {
            float y = (v2 - mu2) * rstd2 * ld<BF>(A.p[I_G2], t) + ld<BF>(A.p[I_BE2], t);
            y *= ld<BF>(A.p[I_MV], n);
            if constexpr (BF) ((u16*)dout)[(size_t)n * Hb + t] = f2b(y);
            else              ((float*)dout)[(size_t)n * Hb + t] = y;
        }
    } else {
        // edge epilogue: LN(h_E + m)
#pragma unroll
        for (int ei = 0; ei < 4; ++ei)
#pragma unroll
            for (int oi = 0; oi < 4; ++oi) mbuf[eb+ei][o0+oi] = acc3[ei][oi];
        __syncthreads();
        const int e = t >> 3, j = t & 7;
        const size_t he_o = (size_t)(n * Kb + e) * Hb;
        float vals[16];
        float s = 0.f;
#pragma unroll
        for (int c = 0; c < 16; ++c) {
            int o = j * 16 + c;
            float x = ld<BF>(hEp, he_o + o) + mbuf[e][o];
            vals[c] = x; s += x;
        }
        s += __shfl_xor(s, 1); s += __shfl_xor(s, 2); s += __shfl_xor(s, 4);
        float mu = s * (1.0f / Hb);
        float q = 0.f;
#pragma unroll
        for (int c = 0; c < 16; ++c) { float dd = vals[c] - mu; q += dd * dd; }
        q += __shfl_xor(q, 1); q += __shfl_xor(q, 2); q += __shfl_xor(q, 4);
        float rstd = 1.0f / sqrtf(q * (1.0f / Hb) + 1e-5f);
        const size_t ob = (size_t)Nn * Hb + he_o;
#pragma unroll
        for (int c = 0; c < 16; ++c) {
            int o = j * 16 + c;
            float y = (vals[c] - mu) * rstd * ld<BF>(gAp, o) + ld<BF>(beAp, o);
            if constexpr (BF) ((u16*)dout)[ob + o] = f2b(y);
            else              ((float*)dout)[ob + o] = y;
        }
    }
}

// ---------------------------------------------------------------------------
extern "C" void kernel_launch(void* const* d_in, const int* in_sizes, int n_in,
                              void* d_out, int out_size, void* d_ws, size_t ws_size,
                              hipStream_t stream) {
    Args A;
    for (int i = 0; i < 32; ++i) A.p[i] = d_in[i];

    // Pass 1 (node update): writes h_V region of d_out.
    k_msg<0, true ><<<Nn, 256, 0, stream>>>(A, d_in[0], d_out);
    k_msg<0, false><<<Nn, 256, 0, stream>>>(A, d_in[0], d_out);
    // Pass 2 (edge update): reads updated h_V from d_out, writes h_E region.
    k_msg<1, true ><<<Nn, 256, 0, stream>>>(A, d_out, d_out);
    k_msg<1, false><<<Nn, 256, 0, stream>>>(A, d_out, d_out);
}